// Round 7
// baseline (288.040 us; speedup 1.0000x reference)
//
#include <hip/hip_runtime.h>

// Causal MHA forward, B=2 T=2048 C=1024 H=16 hs=64, fp32 in/out, bf16 MFMA internally.
// R7: R6's barrier-free one-wave flash with the Opart overflow FIXED: only strips s>=96
// are kv-split (balanced halves), Opart = 8.52 MB and fits the dead xb+wkqvT region
// (14.68 MB) without touching live wprojT.

typedef unsigned short u16;
typedef unsigned int u32;
typedef __bf16 bf16x8 __attribute__((ext_vector_type(8)));
typedef float f32x4 __attribute__((ext_vector_type(4)));
typedef u32 u32x4 __attribute__((ext_vector_type(4)));
typedef u16 u16x4 __attribute__((ext_vector_type(4)));

__device__ __forceinline__ u16 f2bf(float f) {
  u32 u = __float_as_uint(f);
  u32 r = u + 0x7FFFu + ((u >> 16) & 1u);  // RNE, finite inputs only
  return (u16)(r >> 16);
}

__device__ __forceinline__ bf16x8 ld_bf8(const u16* p) {
  union { u32x4 u; bf16x8 b; } x;
  x.u = *(const u32x4*)p;
  return x.b;
}

__device__ __forceinline__ void gld_lds16(const u16* g, u16* l) {
  __builtin_amdgcn_global_load_lds(
      (const __attribute__((address_space(1))) u32*)g,
      (__attribute__((address_space(3))) u32*)l, 16, 0, 0);
}

// ---- fp32 -> bf16, 8 elements/thread ----
__global__ __launch_bounds__(256) void conv_x_kernel(const float* __restrict__ src,
                                                     u16* __restrict__ dst) {
  int idx = blockIdx.x * 256 + threadIdx.x;
  const float4* s4 = (const float4*)src;
  float4 a = s4[2 * idx], b = s4[2 * idx + 1];
  union { u16 h[8]; u32x4 v; } pk;
  pk.h[0] = f2bf(a.x); pk.h[1] = f2bf(a.y); pk.h[2] = f2bf(a.z); pk.h[3] = f2bf(a.w);
  pk.h[4] = f2bf(b.x); pk.h[5] = f2bf(b.y); pk.h[6] = f2bf(b.z); pk.h[7] = f2bf(b.w);
  *(u32x4*)&dst[(size_t)idx * 8] = pk.v;
}

// ---- fp32 (R x Cc) -> bf16 transposed (Cc x R) ----
__global__ __launch_bounds__(256) void convT_kernel(const float* __restrict__ src,
                                                    u16* __restrict__ dst, int R, int Cc) {
  __shared__ float ls[64][65];
  int r0 = blockIdx.x * 64, c0 = blockIdx.y * 64;
  int t = threadIdx.x;
  for (int u = t; u < 1024; u += 256) {
    int r = u >> 4, cs = (u & 15) << 2;
    float4 v = *(const float4*)&src[(size_t)(r0 + r) * Cc + (c0 + cs)];
    ls[r][cs] = v.x; ls[r][cs + 1] = v.y; ls[r][cs + 2] = v.z; ls[r][cs + 3] = v.w;
  }
  __syncthreads();
  for (int u = t; u < 1024; u += 256) {
    int n = u >> 4, ks = (u & 15) << 2;
    u16x4 o;
    o.x = f2bf(ls[ks][n]); o.y = f2bf(ls[ks + 1][n]);
    o.z = f2bf(ls[ks + 2][n]); o.w = f2bf(ls[ks + 3][n]);
    *(u16x4*)&dst[(size_t)(c0 + n) * R + (r0 + ks)] = o;
  }
}

// ---- QKV GEMM: 128x128 tile, 4 waves x (64x64), BK=32, K=1024 (m97 structure) ----
__global__ __launch_bounds__(256) void qkv_gemm_kernel(
    const u16* __restrict__ A, const u16* __restrict__ Bt,
    u16* __restrict__ Qh, u16* __restrict__ Kh, u16* __restrict__ Vh, float qscale) {
  constexpr int K = 1024;
  __shared__ __align__(16) u16 As[128 * 32];
  __shared__ __align__(16) u16 Bs[128 * 32];
  int t = threadIdx.x;
  int wave = t >> 6, lane = t & 63, quad = lane >> 4, l16 = lane & 15;
  int wm = (wave >> 1) << 6, wn = (wave & 1) << 6;
  int m0 = blockIdx.x * 128, n0 = blockIdx.y * 128;
  f32x4 acc[4][4] = {};
  int u0 = t, u1 = t + 256;
  int ra0 = u0 >> 2, ca0 = ((u0 & 3) ^ ((u0 >> 3) & 3)) << 3;
  int ra1 = u1 >> 2, ca1 = ((u1 & 3) ^ ((u1 >> 3) & 3)) << 3;
  int swq = (quad ^ ((l16 >> 1) & 3)) << 3;
  for (int k0 = 0; k0 < K; k0 += 32) {
    gld_lds16(&A[(size_t)(m0 + ra0) * K + k0 + ca0], &As[u0 * 8]);
    gld_lds16(&A[(size_t)(m0 + ra1) * K + k0 + ca1], &As[u1 * 8]);
    gld_lds16(&Bt[(size_t)(n0 + ra0) * K + k0 + ca0], &Bs[u0 * 8]);
    gld_lds16(&Bt[(size_t)(n0 + ra1) * K + k0 + ca1], &Bs[u1 * 8]);
    __syncthreads();
    bf16x8 af[4], bfr[4];
    for (int r = 0; r < 4; ++r) af[r] = ld_bf8(&As[(wm + r * 16 + l16) * 32 + swq]);
    for (int c = 0; c < 4; ++c) bfr[c] = ld_bf8(&Bs[(wn + c * 16 + l16) * 32 + swq]);
    for (int r = 0; r < 4; ++r)
      for (int c = 0; c < 4; ++c)
        acc[r][c] = __builtin_amdgcn_mfma_f32_16x16x32_bf16(af[r], bfr[c], acc[r][c], 0, 0, 0);
    __syncthreads();
  }
  for (int r = 0; r < 4; ++r) {
    int rowbase = m0 + wm + r * 16 + quad * 4;
    for (int c = 0; c < 4; ++c) {
      int col = n0 + wn + c * 16 + l16;
      int seg = col >> 10;
      int cc = col & 1023;
      int h = cc >> 6, d = cc & 63;
      for (int i = 0; i < 4; ++i) {
        int row = rowbase + i;
        int b = row >> 11, tt = row & 2047;
        size_t off = (((size_t)(b * 16 + h)) * 2048 + tt) * 64 + d;
        float v = acc[r][c][i];
        if (seg == 0)      Qh[off] = f2bf(v * qscale);
        else if (seg == 1) Kh[off] = f2bf(v);
        else               Vh[off] = f2bf(v);
      }
    }
  }
}

// ---- bf16 transpose: Vh[bh][2048][64] -> Vt[bh][64][2048] ----
__global__ __launch_bounds__(256) void vT_kernel(const u16* __restrict__ Vh,
                                                 u16* __restrict__ Vt) {
  __shared__ __align__(16) u16 ls[64 * 72];
  int t = threadIdx.x;
  int t0 = blockIdx.x * 64, bh = blockIdx.y;
  const u16* in = Vh + ((size_t)bh * 2048 + t0) * 64;
  for (int u = t; u < 512; u += 256) {
    int row = u >> 3, col = (u & 7) << 3;
    *(u32x4*)&ls[row * 72 + col] = *(const u32x4*)&in[(size_t)row * 64 + col];
  }
  __syncthreads();
  for (int u = t; u < 512; u += 256) {
    int d = u >> 3, tc = (u & 7) << 3;
    union { u16 h[8]; u32x4 v; } pk;
    for (int j = 0; j < 8; ++j) pk.h[j] = ls[(tc + j) * 72 + d];
    *(u32x4*)&Vt[((size_t)bh * 64 + d) * 2048 + t0 + tc] = pk.v;
  }
}

// ---- proj GEMM: 128x128 tile, 8 waves (2x4 grid, wave tile 64x32), grid (32,8) ----
__global__ __launch_bounds__(512) void proj_gemm_kernel(
    const u16* __restrict__ A, const u16* __restrict__ Bt,
    float* __restrict__ out, const float* __restrict__ bias) {
  constexpr int K = 1024;
  __shared__ __align__(16) u16 As[128 * 32];
  __shared__ __align__(16) u16 Bs[128 * 32];
  int t = threadIdx.x;
  int wave = t >> 6, lane = t & 63, quad = lane >> 4, l16 = lane & 15;
  int wm = (wave >> 2) << 6, wn = (wave & 3) << 5;
  int m0 = blockIdx.x * 128, n0 = blockIdx.y * 128;
  f32x4 acc[4][2] = {};
  int u0 = t;
  int ra0 = u0 >> 2, ca0 = ((u0 & 3) ^ ((u0 >> 3) & 3)) << 3;
  int swq = (quad ^ ((l16 >> 1) & 3)) << 3;
  for (int k0 = 0; k0 < K; k0 += 32) {
    gld_lds16(&A[(size_t)(m0 + ra0) * K + k0 + ca0], &As[u0 * 8]);
    gld_lds16(&Bt[(size_t)(n0 + ra0) * K + k0 + ca0], &Bs[u0 * 8]);
    __syncthreads();
    bf16x8 af[4], bfr[2];
    for (int r = 0; r < 4; ++r) af[r] = ld_bf8(&As[(wm + r * 16 + l16) * 32 + swq]);
    for (int c = 0; c < 2; ++c) bfr[c] = ld_bf8(&Bs[(wn + c * 16 + l16) * 32 + swq]);
    for (int r = 0; r < 4; ++r)
      for (int c = 0; c < 2; ++c)
        acc[r][c] = __builtin_amdgcn_mfma_f32_16x16x32_bf16(af[r], bfr[c], acc[r][c], 0, 0, 0);
    __syncthreads();
  }
  for (int r = 0; r < 4; ++r) {
    int rowbase = m0 + wm + r * 16 + quad * 4;
    for (int c = 0; c < 2; ++c) {
      int col = n0 + wn + c * 16 + l16;
      float bv = bias[col];
      for (int i = 0; i < 4; ++i)
        out[(size_t)(rowbase + i) * 1024 + col] = acc[r][c][i] + bv;
    }
  }
}

// ---- flash attention: one wave per 16 q-rows, barrier-free, static-max exp2 softmax ----
// S^T form: A=K-frag / B=Q-frag read DIRECTLY from global (per-lane-contiguous 16B).
// LDS only for the 2KB wave-private P roundtrip (rotation-swizzled).
// Jobs/bh: full strips s=0..95 (<=24 iters); s=96..127 kv-split balanced (<=16 iters each).
__global__ __launch_bounds__(64, 4) void flash_kernel(
    const u16* __restrict__ Qh, const u16* __restrict__ Kh, const u16* __restrict__ Vt,
    u16* __restrict__ yb, float* __restrict__ Opart) {
  __shared__ __align__(16) u16 Ps[16 * 64];  // one wave per block
  int t = threadIdx.x, quad = t >> 4, l16 = t & 15;
  int jx = blockIdx.x, bh = blockIdx.y;
  int s, kvs, kve, half = 0;
  bool partial = false;
  if (jx < 32) {            // longest full strips first: s=95..64 (24..17 iters)
    s = 95 - jx; kvs = 0; kve = (s >> 2) + 1;
  } else if (jx < 96) {     // split strips s=96..127, balanced halves (<=16 iters)
    int idx = jx - 32;
    s = 96 + (idx >> 1); half = idx & 1;
    int n = (s >> 2) + 1, mid = n >> 1;
    kvs = half ? mid : 0; kve = half ? n : mid;
    partial = true;
  } else {                  // remaining full strips: s=63..0 (16..1 iters)
    s = 159 - jx; kvs = 0; kve = (s >> 2) + 1;
  }
  int q0 = s << 4, smax = s >> 2;
  const u16* Qb = Qh + (size_t)bh * 2048 * 64;
  const u16* Kb = Kh + (size_t)bh * 2048 * 64;
  const u16* Vb = Vt + (size_t)bh * 64 * 2048;
  bf16x8 qa0 = ld_bf8(&Qb[(size_t)(q0 + l16) * 64 + quad * 8]);
  bf16x8 qa1 = ld_bf8(&Qb[(size_t)(q0 + l16) * 64 + 32 + quad * 8]);
  f32x4 oacc[4] = {};
  float lsum = 0.f;
  for (int j = kvs; j < kve; ++j) {
    int kv0 = j << 6;
    bf16x8 kb[4][2], vb[4][2];
    for (int c = 0; c < 4; ++c) {          // K-frags: A-operand, direct global 16B/lane
      const u16* kp = &Kb[(size_t)(kv0 + c * 16 + l16) * 64 + quad * 8];
      kb[c][0] = ld_bf8(kp);
      kb[c][1] = ld_bf8(kp + 32);
    }
    for (int dt = 0; dt < 4; ++dt) {       // V^T-frags: B-operand, direct global 16B/lane
      const u16* vp = &Vb[(size_t)(dt * 16 + l16) * 2048 + kv0 + quad * 8];
      vb[dt][0] = ld_bf8(vp);
      vb[dt][1] = ld_bf8(vp + 32);
    }
    bool maskit = (j == smax);
    for (int c = 0; c < 4; ++c) {
      f32x4 z = {0.f, 0.f, 0.f, 0.f};
      z = __builtin_amdgcn_mfma_f32_16x16x32_bf16(kb[c][0], qa0, z, 0, 0, 0);
      z = __builtin_amdgcn_mfma_f32_16x16x32_bf16(kb[c][1], qa1, z, 0, 0, 0);
      union { u16 hh[4]; u16x4 v; } pk;
      for (int i = 0; i < 4; ++i) {
        float p = __builtin_amdgcn_exp2f(z[i]);
        if (maskit && (kv0 + c * 16 + quad * 4 + i > q0 + l16)) p = 0.f;
        lsum += p;
        pk.hh[i] = f2bf(p);
      }
      // C-layout (kv=quad*4+i, q=l16) -> row-major P[q][kv], swizzled chunks
      *(u16x4*)&Ps[l16 * 64 + ((2 * c + (quad >> 1) + l16) & 7) * 8 + (quad & 1) * 4] = pk.v;
    }
    bf16x8 pa0 = ld_bf8(&Ps[l16 * 64 + ((quad + l16) & 7) * 8]);      // A-frag readback
    bf16x8 pa1 = ld_bf8(&Ps[l16 * 64 + ((quad + 4 + l16) & 7) * 8]);
    for (int dt = 0; dt < 4; ++dt) {
      oacc[dt] = __builtin_amdgcn_mfma_f32_16x16x32_bf16(pa0, vb[dt][0], oacc[dt], 0, 0, 0);
      oacc[dt] = __builtin_amdgcn_mfma_f32_16x16x32_bf16(pa1, vb[dt][1], oacc[dt], 0, 0, 0);
    }
  }
  lsum += __shfl_xor(lsum, 16);
  lsum += __shfl_xor(lsum, 32);
  if (partial) {
    float* Op = Opart + ((size_t)(bh * 32 + (s - 96)) * 2 + half) * 1040;
    for (int dt = 0; dt < 4; ++dt)
      for (int i = 0; i < 4; ++i)
        Op[(quad * 4 + i) * 64 + dt * 16 + l16] = oacc[dt][i];
    if (quad == 0) Op[1024 + l16] = lsum;
  } else {
    int b = bh >> 4, h = bh & 15;
    for (int i = 0; i < 4; ++i) {
      float inv = 1.0f / __shfl(lsum, quad * 4 + i);
      int qq = q0 + quad * 4 + i;
      size_t rowoff = ((size_t)(b * 2048 + qq)) * 1024 + h * 64;
      for (int dt = 0; dt < 4; ++dt)
        yb[rowoff + dt * 16 + l16] = f2bf(oacc[dt][i] * inv);
    }
  }
}

// ---- combine split halves: O = O0+O1, l = l0+l1, write normalized bf16 ----
__global__ __launch_bounds__(64) void combine_kernel(const float* __restrict__ Opart,
                                                     u16* __restrict__ yb) {
  int sx = blockIdx.x, bh = blockIdx.y, t = threadIdx.x;
  int s = 96 + sx;
  const float* A = Opart + (size_t)(bh * 32 + sx) * 2 * 1040;
  const float* Bp = A + 1040;
  int r = t >> 2, d0 = (t & 3) << 4;  // 16 rows x 64 cols, 4 threads/row
  float inv = 1.0f / (A[1024 + r] + Bp[1024 + r]);
  int b = bh >> 4, h = bh & 15;
  size_t off = ((size_t)(b * 2048 + (s << 4) + r)) * 1024 + h * 64 + d0;
  union { u16 hh[16]; u32x4 v[2]; } pk;
  for (int k = 0; k < 16; ++k)
    pk.hh[k] = f2bf((A[r * 64 + d0 + k] + Bp[r * 64 + d0 + k]) * inv);
  *(u32x4*)&yb[off] = pk.v[0];
  *(u32x4*)&yb[off + 8] = pk.v[1];
}

extern "C" void kernel_launch(void* const* d_in, const int* in_sizes, int n_in,
                              void* d_out, int out_size, void* d_ws, size_t ws_size,
                              hipStream_t stream) {
  const float* x     = (const float*)d_in[0];
  const float* Wkqv  = (const float*)d_in[1];
  const float* Wproj = (const float*)d_in[2];
  const float* bproj = (const float*)d_in[3];
  float* out = (float*)d_out;

  u16* ws     = (u16*)d_ws;                       // 48 MiB total scratch
  u16* xb     = ws;                               // 4096x1024 bf16 = 8.39 MB (dead after qkv)
  u16* wkqvT  = xb + (size_t)4096 * 1024;         // 3072x1024 = 6.29 MB (dead after qkv)
  u16* wprojT = wkqvT + (size_t)3072 * 1024;      // 1024x1024 (W_proj^T) -- LIVE to the end
  u16* Qh     = wprojT + (size_t)1024 * 1024;     // [32][2048][64], pre-scaled
  u16* Kh     = Qh + (size_t)32 * 2048 * 64;      // [32][2048][64]
  u16* Vt     = Kh + (size_t)32 * 2048 * 64;      // [32][64][2048]
  u16* yb     = Vt + (size_t)32 * 2048 * 64;      // 4096x1024 attn out; doubles as Vh
  u16* Vh     = yb;
  // Opart: 32 bh x 32 strips x 2 halves x 1040 fp32 = 8.52 MB — fits inside the dead
  // xb+wkqvT region (14.68 MB); wprojT is NOT touched (R6's overflow bug).
  float* Opart = (float*)ws;

  const float QSCALE = 0.18033688011112042f;  // (1/sqrt(64)) * log2(e)

  conv_x_kernel<<<2048, 256, 0, stream>>>(x, xb);
  convT_kernel<<<dim3(16, 48), 256, 0, stream>>>(Wkqv, wkqvT, 1024, 3072);
  convT_kernel<<<dim3(16, 16), 256, 0, stream>>>(Wproj, wprojT, 1024, 1024);
  qkv_gemm_kernel<<<dim3(32, 24), 256, 0, stream>>>(xb, wkqvT, Qh, Kh, Vh, QSCALE);
  vT_kernel<<<dim3(32, 32), 256, 0, stream>>>(Vh, Vt);
  flash_kernel<<<dim3(160, 32), 64, 0, stream>>>(Qh, Kh, Vt, yb, Opart);
  combine_kernel<<<dim3(32, 32), 64, 0, stream>>>(Opart, yb);
  proj_gemm_kernel<<<dim3(32, 8), 512, 0, stream>>>(yb, wprojT, out, bproj);
}

// Round 8
// 189.311 us; speedup vs baseline: 1.5215x; 1.5215x over previous
//
#include <hip/hip_runtime.h>

// Causal MHA forward, B=2 T=2048 C=1024 H=16 hs=64, fp32 in/out, bf16 MFMA internally.
// R8: flash = R4's proven BQ=64/4-wave/1440-block structure + R5's rotation swizzle
// (stride 64, conflict-free) + global_load_lds staging (source-permuted addresses,
// lane-linear LDS dest) + XCD-aware job decode (all 45 jobs of a bh on one XCD).

typedef unsigned short u16;
typedef unsigned int u32;
typedef __bf16 bf16x8 __attribute__((ext_vector_type(8)));
typedef float f32x4 __attribute__((ext_vector_type(4)));
typedef u32 u32x4 __attribute__((ext_vector_type(4)));
typedef u16 u16x4 __attribute__((ext_vector_type(4)));

__device__ __forceinline__ u16 f2bf(float f) {
  u32 u = __float_as_uint(f);
  u32 r = u + 0x7FFFu + ((u >> 16) & 1u);  // RNE, finite inputs only
  return (u16)(r >> 16);
}

__device__ __forceinline__ bf16x8 ld_bf8(const u16* p) {
  union { u32x4 u; bf16x8 b; } x;
  x.u = *(const u32x4*)p;
  return x.b;
}

__device__ __forceinline__ void gld_lds16(const u16* g, u16* l) {
  __builtin_amdgcn_global_load_lds(
      (const __attribute__((address_space(1))) u32*)g,
      (__attribute__((address_space(3))) u32*)l, 16, 0, 0);
}

// ---- fp32 -> bf16, 8 elements/thread ----
__global__ __launch_bounds__(256) void conv_x_kernel(const float* __restrict__ src,
                                                     u16* __restrict__ dst) {
  int idx = blockIdx.x * 256 + threadIdx.x;
  const float4* s4 = (const float4*)src;
  float4 a = s4[2 * idx], b = s4[2 * idx + 1];
  union { u16 h[8]; u32x4 v; } pk;
  pk.h[0] = f2bf(a.x); pk.h[1] = f2bf(a.y); pk.h[2] = f2bf(a.z); pk.h[3] = f2bf(a.w);
  pk.h[4] = f2bf(b.x); pk.h[5] = f2bf(b.y); pk.h[6] = f2bf(b.z); pk.h[7] = f2bf(b.w);
  *(u32x4*)&dst[(size_t)idx * 8] = pk.v;
}

// ---- fp32 (R x Cc) -> bf16 transposed (Cc x R) ----
__global__ __launch_bounds__(256) void convT_kernel(const float* __restrict__ src,
                                                    u16* __restrict__ dst, int R, int Cc) {
  __shared__ float ls[64][65];
  int r0 = blockIdx.x * 64, c0 = blockIdx.y * 64;
  int t = threadIdx.x;
  for (int u = t; u < 1024; u += 256) {
    int r = u >> 4, cs = (u & 15) << 2;
    float4 v = *(const float4*)&src[(size_t)(r0 + r) * Cc + (c0 + cs)];
    ls[r][cs] = v.x; ls[r][cs + 1] = v.y; ls[r][cs + 2] = v.z; ls[r][cs + 3] = v.w;
  }
  __syncthreads();
  for (int u = t; u < 1024; u += 256) {
    int n = u >> 4, ks = (u & 15) << 2;
    u16x4 o;
    o.x = f2bf(ls[ks][n]); o.y = f2bf(ls[ks + 1][n]);
    o.z = f2bf(ls[ks + 2][n]); o.w = f2bf(ls[ks + 3][n]);
    *(u16x4*)&dst[(size_t)(c0 + n) * R + (r0 + ks)] = o;
  }
}

// ---- QKV GEMM: 128x128 tile, 4 waves x (64x64), BK=32, K=1024 (m97 structure) ----
__global__ __launch_bounds__(256) void qkv_gemm_kernel(
    const u16* __restrict__ A, const u16* __restrict__ Bt,
    u16* __restrict__ Qh, u16* __restrict__ Kh, u16* __restrict__ Vh, float qscale) {
  constexpr int K = 1024;
  __shared__ __align__(16) u16 As[128 * 32];
  __shared__ __align__(16) u16 Bs[128 * 32];
  int t = threadIdx.x;
  int wave = t >> 6, lane = t & 63, quad = lane >> 4, l16 = lane & 15;
  int wm = (wave >> 1) << 6, wn = (wave & 1) << 6;
  int m0 = blockIdx.x * 128, n0 = blockIdx.y * 128;
  f32x4 acc[4][4] = {};
  int u0 = t, u1 = t + 256;
  int ra0 = u0 >> 2, ca0 = ((u0 & 3) ^ ((u0 >> 3) & 3)) << 3;
  int ra1 = u1 >> 2, ca1 = ((u1 & 3) ^ ((u1 >> 3) & 3)) << 3;
  int swq = (quad ^ ((l16 >> 1) & 3)) << 3;
  for (int k0 = 0; k0 < K; k0 += 32) {
    gld_lds16(&A[(size_t)(m0 + ra0) * K + k0 + ca0], &As[u0 * 8]);
    gld_lds16(&A[(size_t)(m0 + ra1) * K + k0 + ca1], &As[u1 * 8]);
    gld_lds16(&Bt[(size_t)(n0 + ra0) * K + k0 + ca0], &Bs[u0 * 8]);
    gld_lds16(&Bt[(size_t)(n0 + ra1) * K + k0 + ca1], &Bs[u1 * 8]);
    __syncthreads();
    bf16x8 af[4], bfr[4];
    for (int r = 0; r < 4; ++r) af[r] = ld_bf8(&As[(wm + r * 16 + l16) * 32 + swq]);
    for (int c = 0; c < 4; ++c) bfr[c] = ld_bf8(&Bs[(wn + c * 16 + l16) * 32 + swq]);
    for (int r = 0; r < 4; ++r)
      for (int c = 0; c < 4; ++c)
        acc[r][c] = __builtin_amdgcn_mfma_f32_16x16x32_bf16(af[r], bfr[c], acc[r][c], 0, 0, 0);
    __syncthreads();
  }
  for (int r = 0; r < 4; ++r) {
    int rowbase = m0 + wm + r * 16 + quad * 4;
    for (int c = 0; c < 4; ++c) {
      int col = n0 + wn + c * 16 + l16;
      int seg = col >> 10;
      int cc = col & 1023;
      int h = cc >> 6, d = cc & 63;
      for (int i = 0; i < 4; ++i) {
        int row = rowbase + i;
        int b = row >> 11, tt = row & 2047;
        size_t off = (((size_t)(b * 16 + h)) * 2048 + tt) * 64 + d;
        float v = acc[r][c][i];
        if (seg == 0)      Qh[off] = f2bf(v * qscale);
        else if (seg == 1) Kh[off] = f2bf(v);
        else               Vh[off] = f2bf(v);
      }
    }
  }
}

// ---- bf16 transpose: Vh[bh][2048][64] -> Vt[bh][64][2048] ----
__global__ __launch_bounds__(256) void vT_kernel(const u16* __restrict__ Vh,
                                                 u16* __restrict__ Vt) {
  __shared__ __align__(16) u16 ls[64 * 72];
  int t = threadIdx.x;
  int t0 = blockIdx.x * 64, bh = blockIdx.y;
  const u16* in = Vh + ((size_t)bh * 2048 + t0) * 64;
  for (int u = t; u < 512; u += 256) {
    int row = u >> 3, col = (u & 7) << 3;
    *(u32x4*)&ls[row * 72 + col] = *(const u32x4*)&in[(size_t)row * 64 + col];
  }
  __syncthreads();
  for (int u = t; u < 512; u += 256) {
    int d = u >> 3, tc = (u & 7) << 3;
    union { u16 h[8]; u32x4 v; } pk;
    for (int j = 0; j < 8; ++j) pk.h[j] = ls[(tc + j) * 72 + d];
    *(u32x4*)&Vt[((size_t)bh * 64 + d) * 2048 + t0 + tc] = pk.v;
  }
}

// ---- proj GEMM: 128x128 tile, 8 waves (2x4 grid, wave tile 64x32), grid (32,8) ----
__global__ __launch_bounds__(512) void proj_gemm_kernel(
    const u16* __restrict__ A, const u16* __restrict__ Bt,
    float* __restrict__ out, const float* __restrict__ bias) {
  constexpr int K = 1024;
  __shared__ __align__(16) u16 As[128 * 32];
  __shared__ __align__(16) u16 Bs[128 * 32];
  int t = threadIdx.x;
  int wave = t >> 6, lane = t & 63, quad = lane >> 4, l16 = lane & 15;
  int wm = (wave >> 2) << 6, wn = (wave & 3) << 5;
  int m0 = blockIdx.x * 128, n0 = blockIdx.y * 128;
  f32x4 acc[4][2] = {};
  int u0 = t;
  int ra0 = u0 >> 2, ca0 = ((u0 & 3) ^ ((u0 >> 3) & 3)) << 3;
  int swq = (quad ^ ((l16 >> 1) & 3)) << 3;
  for (int k0 = 0; k0 < K; k0 += 32) {
    gld_lds16(&A[(size_t)(m0 + ra0) * K + k0 + ca0], &As[u0 * 8]);
    gld_lds16(&Bt[(size_t)(n0 + ra0) * K + k0 + ca0], &Bs[u0 * 8]);
    __syncthreads();
    bf16x8 af[4], bfr[2];
    for (int r = 0; r < 4; ++r) af[r] = ld_bf8(&As[(wm + r * 16 + l16) * 32 + swq]);
    for (int c = 0; c < 2; ++c) bfr[c] = ld_bf8(&Bs[(wn + c * 16 + l16) * 32 + swq]);
    for (int r = 0; r < 4; ++r)
      for (int c = 0; c < 2; ++c)
        acc[r][c] = __builtin_amdgcn_mfma_f32_16x16x32_bf16(af[r], bfr[c], acc[r][c], 0, 0, 0);
    __syncthreads();
  }
  for (int r = 0; r < 4; ++r) {
    int rowbase = m0 + wm + r * 16 + quad * 4;
    for (int c = 0; c < 2; ++c) {
      int col = n0 + wn + c * 16 + l16;
      float bv = bias[col];
      for (int i = 0; i < 4; ++i)
        out[(size_t)(rowbase + i) * 1024 + col] = acc[r][c][i] + bv;
    }
  }
}

// ---- flash attention: BQ=64, 4 waves x 16 q-rows, S^T form, static-max exp2 softmax ----
// LDS: Ks/Vs/Ps 64x64 u16 stride-64, rotation swizzle: chunk cb of row r at pos (cb+r)&7.
// Staging via global_load_lds with SOURCE-permuted addresses (LDS dest lane-linear).
// 1-D grid, XCD-grouped: all 45 jobs of a bh land on one XCD (id%8 residue).
__global__ __launch_bounds__(256, 6) void flash_kernel(
    const u16* __restrict__ Qh, const u16* __restrict__ Kh, const u16* __restrict__ Vt,
    u16* __restrict__ yb, float* __restrict__ Opart) {
  __shared__ __align__(16) u16 Ks[64 * 64];
  __shared__ __align__(16) u16 Vs[64 * 64];
  __shared__ __align__(16) u16 Ps[64 * 64];
  int t = threadIdx.x, wave = t >> 6, lane = t & 63, quad = lane >> 4, l16 = lane & 15;
  int id = blockIdx.x;                 // 0..1439
  int g = id / 360, r = id % 360;
  int bh = g * 8 + (r & 7);            // same-bh jobs share an XCD (id % 8 constant)
  int jx = r >> 3;                     // 0..44, longest jobs first
  int qtile, kvs, kve, sidx = 0, half = 0;
  bool partial;
  if (jx < 19) {                       // full jobs: qtile 18..0 (19..1 iters)
    qtile = 18 - jx; kvs = 0; kve = qtile + 1; partial = false;
  } else {                             // split jobs: qtile 31..19, 2 halves (<=16 iters)
    sidx = (jx - 19) >> 1; half = (jx - 19) & 1;
    qtile = 31 - sidx;
    int nkv = qtile + 1, mid = nkv >> 1;
    kvs = half ? mid : 0; kve = half ? nkv : mid; partial = true;
  }
  int q0 = qtile << 6;
  const u16* Qb = Qh + (size_t)bh * 2048 * 64;
  const u16* Kb = Kh + (size_t)bh * 2048 * 64;
  const u16* Vb = Vt + (size_t)bh * 64 * 2048;
  bf16x8 qa0, qa1;  // B-operand frags (S^T form)
  {
    int qrow = q0 + wave * 16 + l16;
    qa0 = ld_bf8(&Qb[(size_t)qrow * 64 + quad * 8]);
    qa1 = ld_bf8(&Qb[(size_t)qrow * 64 + 32 + quad * 8]);
  }
  f32x4 oacc[4] = {};
  float lsum = 0.f;
  // staging: 512 units of 16B per tile; wave w owns units [w*128, w*128+128), 2/lane.
  // LDS dest lane-linear (unit u at offset u*16B); source chunk cb = (pos - row)&7.
  int u0 = wave * 128 + lane, u1 = u0 + 64;
  int r0 = u0 >> 3, p0 = u0 & 7, cb0 = (p0 - r0) & 7;
  int r1s = u1 >> 3, p1 = u1 & 7, cb1 = (p1 - r1s) & 7;
  for (int j = kvs; j < kve; ++j) {
    int kv0 = j << 6;
    __syncthreads();  // previous tile fully consumed
    gld_lds16(&Kb[(size_t)(kv0 + r0) * 64 + cb0 * 8], &Ks[u0 * 8]);
    gld_lds16(&Kb[(size_t)(kv0 + r1s) * 64 + cb1 * 8], &Ks[u1 * 8]);
    gld_lds16(&Vb[(size_t)r0 * 2048 + kv0 + cb0 * 8], &Vs[u0 * 8]);
    gld_lds16(&Vb[(size_t)r1s * 2048 + kv0 + cb1 * 8], &Vs[u1 * 8]);
    __syncthreads();  // vmcnt(0) drain -> tiles ready
    bool maskit = (j == qtile);
    for (int c = 0; c < 4; ++c) {
      int krow = c * 16 + l16;
      bf16x8 kb0 = ld_bf8(&Ks[krow * 64 + ((quad + krow) & 7) * 8]);
      bf16x8 kb1 = ld_bf8(&Ks[krow * 64 + ((quad + 4 + krow) & 7) * 8]);
      f32x4 z = {0.f, 0.f, 0.f, 0.f};
      z = __builtin_amdgcn_mfma_f32_16x16x32_bf16(kb0, qa0, z, 0, 0, 0);
      z = __builtin_amdgcn_mfma_f32_16x16x32_bf16(kb1, qa1, z, 0, 0, 0);
      int prow = wave * 16 + l16;  // q-local row (wave-private strip)
      union { u16 hh[4]; u16x4 v; } pk;
      for (int i = 0; i < 4; ++i) {
        float p = __builtin_amdgcn_exp2f(z[i]);
        if (maskit && (kv0 + c * 16 + quad * 4 + i > q0 + wave * 16 + l16)) p = 0.f;
        lsum += p;
        pk.hh[i] = f2bf(p);
      }
      // logical chunk 2c+(quad>>1), sub-offset (quad&1)*4, rotated by prow
      *(u16x4*)&Ps[prow * 64 + ((2 * c + (quad >> 1) + prow) & 7) * 8 + (quad & 1) * 4] = pk.v;
    }
    int prow = wave * 16 + l16;
    bf16x8 pa0 = ld_bf8(&Ps[prow * 64 + ((quad + prow) & 7) * 8]);      // A-frag readback
    bf16x8 pa1 = ld_bf8(&Ps[prow * 64 + ((quad + 4 + prow) & 7) * 8]);
    for (int dt = 0; dt < 4; ++dt) {
      int vrow = dt * 16 + l16;
      bf16x8 vb0 = ld_bf8(&Vs[vrow * 64 + ((quad + vrow) & 7) * 8]);
      bf16x8 vb1 = ld_bf8(&Vs[vrow * 64 + ((quad + 4 + vrow) & 7) * 8]);
      oacc[dt] = __builtin_amdgcn_mfma_f32_16x16x32_bf16(pa0, vb0, oacc[dt], 0, 0, 0);
      oacc[dt] = __builtin_amdgcn_mfma_f32_16x16x32_bf16(pa1, vb1, oacc[dt], 0, 0, 0);
    }
  }
  // lsum: lane partial for q=l16 within wave strip; reduce across quad groups
  lsum += __shfl_xor(lsum, 16);
  lsum += __shfl_xor(lsum, 32);
  if (partial) {
    float* Op = Opart + ((size_t)(bh * 13 + sidx) * 2 + half) * 4160;
    for (int dt = 0; dt < 4; ++dt)
      for (int i = 0; i < 4; ++i)
        Op[(wave * 16 + quad * 4 + i) * 64 + dt * 16 + l16] = oacc[dt][i];
    if (quad == 0) Op[4096 + wave * 16 + l16] = lsum;
  } else {
    int b = bh >> 4, h = bh & 15;
    for (int i = 0; i < 4; ++i) {
      float inv = 1.0f / __shfl(lsum, quad * 4 + i);
      int qq = q0 + wave * 16 + quad * 4 + i;
      size_t rowoff = ((size_t)(b * 2048 + qq)) * 1024 + h * 64;
      for (int dt = 0; dt < 4; ++dt)
        yb[rowoff + dt * 16 + l16] = f2bf(oacc[dt][i] * inv);
    }
  }
}

// ---- combine split halves: O = O0+O1, l = l0+l1, write normalized bf16 ----
__global__ __launch_bounds__(256) void combine_kernel(const float* __restrict__ Opart,
                                                      u16* __restrict__ yb) {
  int sidx = blockIdx.x, bh = blockIdx.y, t = threadIdx.x;
  int qtile = 31 - sidx;
  const float* A = Opart + (size_t)(bh * 13 + sidx) * 2 * 4160;
  const float* Bp = A + 4160;
  int q = t >> 2, d0 = (t & 3) << 4;  // 64 rows x 64 cols, 4 threads/row
  float inv = 1.0f / (A[4096 + q] + Bp[4096 + q]);
  int b = bh >> 4, h = bh & 15;
  size_t off = ((size_t)(b * 2048 + (qtile << 6) + q)) * 1024 + h * 64 + d0;
  union { u16 hh[16]; u32x4 v[2]; } pk;
  for (int k = 0; k < 16; ++k)
    pk.hh[k] = f2bf((A[q * 64 + d0 + k] + Bp[q * 64 + d0 + k]) * inv);
  *(u32x4*)&yb[off] = pk.v[0];
  *(u32x4*)&yb[off + 8] = pk.v[1];
}

extern "C" void kernel_launch(void* const* d_in, const int* in_sizes, int n_in,
                              void* d_out, int out_size, void* d_ws, size_t ws_size,
                              hipStream_t stream) {
  const float* x     = (const float*)d_in[0];
  const float* Wkqv  = (const float*)d_in[1];
  const float* Wproj = (const float*)d_in[2];
  const float* bproj = (const float*)d_in[3];
  float* out = (float*)d_out;

  u16* ws     = (u16*)d_ws;                       // 48 MiB total scratch
  u16* xb     = ws;                               // 4096x1024 bf16 = 8.39 MB (dead after qkv)
  u16* wkqvT  = xb + (size_t)4096 * 1024;         // 3072x1024 = 6.29 MB (dead after qkv)
  u16* wprojT = wkqvT + (size_t)3072 * 1024;      // 1024x1024 (W_proj^T) -- LIVE to the end
  u16* Qh     = wprojT + (size_t)1024 * 1024;     // [32][2048][64], pre-scaled
  u16* Kh     = Qh + (size_t)32 * 2048 * 64;      // [32][2048][64]
  u16* Vt     = Kh + (size_t)32 * 2048 * 64;      // [32][64][2048]
  u16* yb     = Vt + (size_t)32 * 2048 * 64;      // 4096x1024 attn out; doubles as Vh
  u16* Vh     = yb;
  // Opart: 32 bh x 13 split-tiles x 2 halves x 4160 fp32 = 13.84 MB — fits the dead
  // xb+wkqvT region (14.68 MB); wprojT untouched (R4-verified layout).
  float* Opart = (float*)ws;

  const float QSCALE = 0.18033688011112042f;  // (1/sqrt(64)) * log2(e)

  conv_x_kernel<<<2048, 256, 0, stream>>>(x, xb);
  convT_kernel<<<dim3(16, 48), 256, 0, stream>>>(Wkqv, wkqvT, 1024, 3072);
  convT_kernel<<<dim3(16, 16), 256, 0, stream>>>(Wproj, wprojT, 1024, 1024);
  qkv_gemm_kernel<<<dim3(32, 24), 256, 0, stream>>>(xb, wkqvT, Qh, Kh, Vh, QSCALE);
  vT_kernel<<<dim3(32, 32), 256, 0, stream>>>(Vh, Vt);
  flash_kernel<<<1440, 256, 0, stream>>>(Qh, Kh, Vt, yb, Opart);
  combine_kernel<<<dim3(13, 32), 256, 0, stream>>>(Opart, yb);
  proj_gemm_kernel<<<dim3(32, 8), 512, 0, stream>>>(yb, wprojT, out, bproj);
}